// Round 2
// baseline (321.513 us; speedup 1.0000x reference)
//
#include <hip/hip_runtime.h>
#include <hip/hip_bf16.h>
#include <math.h>

// Problem constants (fixed by setup_inputs)
#define BATCH 16
#define LEN   262144
#define NFFT  1024
#define HOP   256
#define PADW  512          // n_fft/2
#define NFREQ 513          // rfft bins
#define NFRM  1025         // frames
#define PS    16
#define NPT   65           // ceil(1025/16)
#define NPATCH 2145        // 33*65
#define TOPK  643          // int(2145*0.3)
#define EPSV  1e-8f

// LDS bank-conflict swizzle: element i (float2, 8B) lives at phys i^((i>>4)&15).
// Keeps every radix-4 stage's 64-lane access spread across all 16 bank-pairs.
#define SW(i) ((i) ^ (((i) >> 4) & 15))

// ---------------------------------------------------------------------------
// Kernel 1: STFT magnitude. One block = one (waveform, batch, frame).
// 1024-pt radix-4 DIF complex FFT in LDS (5 stages, 1 butterfly/thread/stage).
// Natural-order input, base-4 digit-reversed output.
// mag layout: [w][b][t][f], f contiguous (coalesced writes).
// ---------------------------------------------------------------------------
__global__ __launch_bounds__(256) void stft_mag_kernel(
    const float* __restrict__ s_in,
    const float* __restrict__ t_in,
    const float* __restrict__ g_in,
    float* __restrict__ mag)
{
    __shared__ float2 xs[1024];
    __shared__ float2 tw[768];   // tw[j] = exp(-2*pi*i*j/1024), j<768 (max m*pos*(1024/len)=765)

    const int tid   = threadIdx.x;
    const int frame = blockIdx.x;   // 0..1024
    const int b     = blockIdx.y;   // 0..15
    const int w     = blockIdx.z;   // 0..2

    const float* src = (w == 0) ? s_in : (w == 1) ? t_in : g_in;
    src += (size_t)b * LEN;

    for (int j = tid; j < 768; j += 256) {
        float sv, cv;
        sincosf(-6.283185307179586476925f * (float)j * (1.0f / 1024.0f), &sv, &cv);
        tw[SW(j)] = make_float2(cv, sv);
    }

    // load frame with reflect padding (jnp 'reflect': no edge repeat)
    const int start = frame * HOP - PADW;
    #pragma unroll
    for (int m = 0; m < 4; ++m) {
        const int i = tid + 256 * m;
        int g = start + i;
        g = (g < 0) ? -g : g;
        g = (g >= LEN) ? (2 * LEN - 2 - g) : g;
        xs[SW(i)] = make_float2(src[g], 0.0f);
    }
    __syncthreads();

    // 5 radix-4 DIF stages. Stage s: len = 1024>>(2s), q = len/4.
    // y_m[pos] = (sum_j x[pos+j*q] * w4^{mj}) * W^{m*pos},  W = exp(-2pi i/len)
    // stored at i0 + m*q.  w4 = -i.
    #pragma unroll
    for (int s = 0; s < 5; ++s) {
        const int lenlog = 10 - 2 * s;
        const int q      = 1 << (lenlog - 2);
        const int pos    = tid & (q - 1);
        const int blk    = tid >> (lenlog - 2);
        const int i0     = (blk << lenlog) + pos;

        float2 a = xs[SW(i0)];
        float2 bb = xs[SW(i0 + q)];
        float2 c = xs[SW(i0 + 2 * q)];
        float2 d = xs[SW(i0 + 3 * q)];

        const float t0x = a.x + c.x,  t0y = a.y + c.y;   // a+c
        const float t1x = a.x - c.x,  t1y = a.y - c.y;   // a-c
        const float t2x = bb.x + d.x, t2y = bb.y + d.y;  // b+d
        const float t3x = bb.x - d.x, t3y = bb.y - d.y;  // b-d

        // y0 = t0+t2 ; y1 = t1 - i*t3 ; y2 = t0-t2 ; y3 = t1 + i*t3
        const float y0x = t0x + t2x, y0y = t0y + t2y;
        const float y1x = t1x + t3y, y1y = t1y - t3x;
        const float y2x = t0x - t2x, y2y = t0y - t2y;
        const float y3x = t1x - t3y, y3y = t1y + t3x;

        const int e  = pos << (2 * s);   // twiddle exponent unit: m*pos*(1024/len)
        const float2 w1 = tw[SW(e)];
        const float2 w2 = tw[SW(2 * e)];
        const float2 w3 = tw[SW(3 * e)];

        xs[SW(i0)]         = make_float2(y0x, y0y);
        xs[SW(i0 + q)]     = make_float2(y1x * w1.x - y1y * w1.y, y1x * w1.y + y1y * w1.x);
        xs[SW(i0 + 2 * q)] = make_float2(y2x * w2.x - y2y * w2.y, y2x * w2.y + y2y * w2.x);
        xs[SW(i0 + 3 * q)] = make_float2(y3x * w3.x - y3y * w3.y, y3x * w3.y + y3y * w3.x);
        __syncthreads();
    }

    // magnitudes, k = 0..512 ; X[k] sits at base-4 digit-reversed slot
    float* out = mag + (((size_t)w * BATCH + b) * NFRM + frame) * NFREQ;
    for (int k = tid; k < NFREQ; k += 256) {
        const unsigned r = __brev((unsigned)k) >> 22;                  // 10-bit bit reversal
        const unsigned p = ((r & 0x155u) << 1) | ((r & 0x2AAu) >> 1);  // swap bit pairs -> base-4 digit reversal
        float2 v = xs[SW(p)];
        out[k] = fmaxf(sqrtf(v.x * v.x + v.y * v.y), EPSV);
    }
}

// ---------------------------------------------------------------------------
// Kernel 2: per-patch stats. One block = one (batch, patch); 256 threads,
// one element each. Out-of-range (f>=513 or t>=1025) contributes 0 (zero-pad
// happens AFTER the EPS clamp in the reference).
// ---------------------------------------------------------------------------
__global__ __launch_bounds__(256) void patch_stats_kernel(
    const float* __restrict__ mag,
    float* __restrict__ kgs,
    float* __restrict__ pl)
{
    const int tid = threadIdx.x;
    const int p   = blockIdx.x;   // 0..2144
    const int b   = blockIdx.y;   // 0..15
    const int fi  = p / NPT;
    const int ti  = p - fi * NPT;
    const int f   = fi * PS + (tid & 15);
    const int t   = ti * PS + (tid >> 4);

    float sv = 0.0f, tv = 0.0f, gv = 0.0f;
    if (f < NFREQ && t < NFRM) {
        const size_t WOFF = (size_t)BATCH * NFRM * NFREQ;
        const size_t base = ((size_t)b * NFRM + t) * NFREQ + f;
        sv = mag[base];
        tv = mag[base + WOFF];
        gv = mag[base + 2 * WOFF];
    }
    float as = fabsf(sv - gv);
    float at = fabsf(tv - gv);
    float sq = (sv - tv) * (sv - tv);

    #pragma unroll
    for (int off = 32; off > 0; off >>= 1) {
        as += __shfl_down(as, off);
        at += __shfl_down(at, off);
        sq += __shfl_down(sq, off);
    }
    __shared__ float red[3][4];
    if ((tid & 63) == 0) {
        const int wv = tid >> 6;
        red[0][wv] = as; red[1][wv] = at; red[2][wv] = sq;
    }
    __syncthreads();
    if (tid == 0) {
        float sas = red[0][0] + red[0][1] + red[0][2] + red[0][3];
        float sat = red[1][0] + red[1][1] + red[1][2] + red[1][3];
        float ssq = red[2][0] + red[2][1] + red[2][2] + red[2][3];
        kgs[b * NPATCH + p] = (sas - sat) * (1.0f / 256.0f);
        pl [b * NPATCH + p] = ssq * (1.0f / 256.0f);
    }
}

// ---------------------------------------------------------------------------
// Kernel 3: per-row top-k. One block per batch row, 1024 threads.
// Key-value bitonic sort of 4096 (padded) with jax tie-break:
// rank order = descending value, ascending index.
// ---------------------------------------------------------------------------
__global__ __launch_bounds__(1024) void topk_kernel(
    const float* __restrict__ kgs,
    const float* __restrict__ pl,
    float* __restrict__ rowstats)  // [16][3] = {selected_sum, kgs_sum, pos_count}
{
    __shared__ float vals[4096];
    __shared__ int   idxs[4096];
    __shared__ float red[3][16];

    const int tid = threadIdx.x;
    const int b   = blockIdx.x;
    const float* row = kgs + b * NPATCH;

    float lsum = 0.0f;
    float lpos = 0.0f;
    for (int i = tid; i < 4096; i += 1024) {
        float v;
        if (i < NPATCH) {
            v = row[i];
            lsum += v;
            lpos += (v > 0.0f) ? 1.0f : 0.0f;
        } else {
            v = -3.402823466e38f;
        }
        vals[i] = v;
        idxs[i] = i;
    }
    __syncthreads();

    for (int k = 2; k <= 4096; k <<= 1) {
        for (int j = k >> 1; j > 0; j >>= 1) {
            for (int i = tid; i < 4096; i += 1024) {
                const int ixj = i ^ j;
                if (ixj > i) {
                    float v0 = vals[i], v1 = vals[ixj];
                    int   d0 = idxs[i], d1 = idxs[ixj];
                    bool before = (v0 > v1) || (v0 == v1 && d0 < d1);
                    bool dirAsc = ((i & k) == 0);
                    if (before != dirAsc) {
                        vals[i] = v1; vals[ixj] = v0;
                        idxs[i] = d1; idxs[ixj] = d0;
                    }
                }
            }
            __syncthreads();
        }
    }

    const float* plrow = pl + b * NPATCH;
    float ssum = 0.0f;
    for (int r = tid; r < TOPK; r += 1024) ssum += plrow[idxs[r]];

    #pragma unroll
    for (int off = 32; off > 0; off >>= 1) {
        ssum += __shfl_down(ssum, off);
        lsum += __shfl_down(lsum, off);
        lpos += __shfl_down(lpos, off);
    }
    if ((tid & 63) == 0) {
        const int wv = tid >> 6;
        red[0][wv] = ssum; red[1][wv] = lsum; red[2][wv] = lpos;
    }
    __syncthreads();
    if (tid == 0) {
        float a = 0, c = 0, d = 0;
        #pragma unroll
        for (int i = 0; i < 16; ++i) { a += red[0][i]; c += red[1][i]; d += red[2][i]; }
        rowstats[b * 3 + 0] = a;
        rowstats[b * 3 + 1] = c;
        rowstats[b * 3 + 2] = d;
    }
}

// ---------------------------------------------------------------------------
// Kernel 4: final reduction over 16 rows -> 4 scalars.
// ---------------------------------------------------------------------------
__global__ __launch_bounds__(64) void final_kernel(
    const float* __restrict__ rowstats,
    float* __restrict__ out)
{
    const int tid = threadIdx.x;
    float loss = 0.0f, ks = 0.0f, pc = 0.0f;
    if (tid < BATCH) {
        loss = rowstats[tid * 3 + 0] * (1.0f / (float)TOPK);
        ks   = rowstats[tid * 3 + 1];
        pc   = rowstats[tid * 3 + 2];
    }
    #pragma unroll
    for (int off = 32; off > 0; off >>= 1) {
        loss += __shfl_down(loss, off);
        ks   += __shfl_down(ks, off);
        pc   += __shfl_down(pc, off);
    }
    if (tid == 0) {
        out[0] = loss * (1.0f / (float)BATCH);
        out[1] = (float)TOPK / (float)NPATCH;
        out[2] = ks * (1.0f / ((float)BATCH * (float)NPATCH));
        out[3] = pc * (1.0f / ((float)BATCH * (float)NPATCH));
    }
}

// ---------------------------------------------------------------------------
extern "C" void kernel_launch(void* const* d_in, const int* in_sizes, int n_in,
                              void* d_out, int out_size, void* d_ws, size_t ws_size,
                              hipStream_t stream)
{
    const float* s_in = (const float*)d_in[0];
    const float* t_in = (const float*)d_in[1];
    const float* g_in = (const float*)d_in[2];
    float* out = (float*)d_out;

    const size_t magElems = (size_t)3 * BATCH * NFRM * NFREQ;  // 25,239,600
    float* mag = (float*)d_ws;
    float* kgs = mag + magElems;
    float* pl  = kgs + (size_t)BATCH * NPATCH;
    float* rowstats = pl + (size_t)BATCH * NPATCH;

    dim3 g1(NFRM, BATCH, 3);
    stft_mag_kernel<<<g1, 256, 0, stream>>>(s_in, t_in, g_in, mag);

    dim3 g2(NPATCH, BATCH, 1);
    patch_stats_kernel<<<g2, 256, 0, stream>>>(mag, kgs, pl);

    topk_kernel<<<BATCH, 1024, 0, stream>>>(kgs, pl, rowstats);

    final_kernel<<<1, 64, 0, stream>>>(rowstats, out);
}

// Round 3
// 212.812 us; speedup vs baseline: 1.5108x; 1.5108x over previous
//
#include <hip/hip_runtime.h>
#include <hip/hip_bf16.h>
#include <math.h>

// Problem constants (fixed by setup_inputs)
#define BATCH 16
#define LEN   262144
#define NFFT  1024
#define HOP   256
#define PADW  512          // n_fft/2
#define NFREQ 513          // rfft bins
#define NFRM  1025         // frames
#define PS    16
#define NPT   65           // ceil(1025/16)
#define NPATCH 2145        // 33*65
#define TOPK  643          // int(2145*0.3)
#define EPSV  1e-8f

// LDS bank-conflict swizzle: element i (float2, 8B) lives at phys i^((i>>4)&15).
#define SW(i) ((i) ^ (((i) >> 4) & 15))

// ---------------------------------------------------------------------------
// Kernel 1: STFT magnitude, 2 frames packed per complex FFT.
// One block = one (waveform, batch, frame-pair). z = frameA + i*frameB.
// 1024-pt radix-4 DIF complex FFT in LDS (5 stages).
// Unpack: A[k] = (Z[k]+conj(Z[N-k]))/2 ; B[k] = (Z[k]-conj(Z[N-k]))/(2i).
// mag layout: [w][b][t][f], f contiguous.
// ---------------------------------------------------------------------------
__global__ __launch_bounds__(256) void stft_mag_kernel(
    const float* __restrict__ s_in,
    const float* __restrict__ t_in,
    const float* __restrict__ g_in,
    float* __restrict__ mag)
{
    __shared__ float2 xs[1024];
    __shared__ float2 tw[768];   // tw[j] = exp(-2*pi*i*j/1024)

    const int tid = threadIdx.x;
    const int p   = blockIdx.x;   // frame pair: frames 2p, 2p+1 ; 0..512
    const int b   = blockIdx.y;   // 0..15
    const int w   = blockIdx.z;   // 0..2

    const float* src = (w == 0) ? s_in : (w == 1) ? t_in : g_in;
    src += (size_t)b * LEN;

    // One sincos per thread; tw[j+256] = -i*tw[j]; tw[j+512] = -tw[j].
    {
        float sv, cv;
        sincosf(-6.283185307179586476925f * (float)tid * (1.0f / 1024.0f), &sv, &cv);
        tw[SW(tid)]       = make_float2(cv, sv);
        tw[SW(tid + 256)] = make_float2(sv, -cv);
        tw[SW(tid + 512)] = make_float2(-cv, -sv);
    }

    const bool hasB  = (2 * p + 1) < NFRM;
    const int startA = 2 * p * HOP - PADW;

    // load both frames with reflect padding (jnp 'reflect': no edge repeat)
    #pragma unroll
    for (int m = 0; m < 4; ++m) {
        const int i = tid + 256 * m;
        int ga = startA + i;
        ga = (ga < 0) ? -ga : ga;
        ga = (ga >= LEN) ? (2 * LEN - 2 - ga) : ga;
        float re = src[ga];
        float im = 0.0f;
        if (hasB) {
            int gb = startA + HOP + i;
            gb = (gb < 0) ? -gb : gb;
            gb = (gb >= LEN) ? (2 * LEN - 2 - gb) : gb;
            im = src[gb];
        }
        xs[SW(i)] = make_float2(re, im);
    }
    __syncthreads();

    // 5 radix-4 DIF stages (w4 = -i). Natural input, base-4 digit-reversed output.
    #pragma unroll
    for (int s = 0; s < 5; ++s) {
        const int lenlog = 10 - 2 * s;
        const int q      = 1 << (lenlog - 2);
        const int pos    = tid & (q - 1);
        const int blk    = tid >> (lenlog - 2);
        const int i0     = (blk << lenlog) + pos;

        float2 a  = xs[SW(i0)];
        float2 bb = xs[SW(i0 + q)];
        float2 c  = xs[SW(i0 + 2 * q)];
        float2 d  = xs[SW(i0 + 3 * q)];

        const float t0x = a.x + c.x,  t0y = a.y + c.y;
        const float t1x = a.x - c.x,  t1y = a.y - c.y;
        const float t2x = bb.x + d.x, t2y = bb.y + d.y;
        const float t3x = bb.x - d.x, t3y = bb.y - d.y;

        const float y0x = t0x + t2x, y0y = t0y + t2y;
        const float y1x = t1x + t3y, y1y = t1y - t3x;
        const float y2x = t0x - t2x, y2y = t0y - t2y;
        const float y3x = t1x - t3y, y3y = t1y + t3x;

        const int e  = pos << (2 * s);
        const float2 w1 = tw[SW(e)];
        const float2 w2 = tw[SW(2 * e)];
        const float2 w3 = tw[SW(3 * e)];

        xs[SW(i0)]         = make_float2(y0x, y0y);
        xs[SW(i0 + q)]     = make_float2(y1x * w1.x - y1y * w1.y, y1x * w1.y + y1y * w1.x);
        xs[SW(i0 + 2 * q)] = make_float2(y2x * w2.x - y2y * w2.y, y2x * w2.y + y2y * w2.x);
        xs[SW(i0 + 3 * q)] = make_float2(y3x * w3.x - y3y * w3.y, y3x * w3.y + y3y * w3.x);
        __syncthreads();
    }

    // unpack + magnitudes for both frames
    float* outA = mag + (((size_t)w * BATCH + b) * NFRM + 2 * p) * NFREQ;
    for (int k = tid; k < NFREQ; k += 256) {
        const unsigned rk = __brev((unsigned)k) >> 22;
        const unsigned pk = ((rk & 0x155u) << 1) | ((rk & 0x2AAu) >> 1);
        const unsigned mI = (unsigned)(1024 - k) & 1023u;
        const unsigned rm = __brev(mI) >> 22;
        const unsigned pm = ((rm & 0x155u) << 1) | ((rm & 0x2AAu) >> 1);
        const float2 Zk = xs[SW(pk)];
        const float2 Zm = xs[SW(pm)];
        const float ar = Zk.x + Zm.x, ai = Zk.y - Zm.y;   // 2*A[k]
        const float br = Zk.y + Zm.y, bi = Zk.x - Zm.x;   // 2*B[k] (up to sign on im)
        outA[k] = fmaxf(0.5f * sqrtf(ar * ar + ai * ai), EPSV);
        if (hasB) outA[NFREQ + k] = fmaxf(0.5f * sqrtf(br * br + bi * bi), EPSV);
    }
}

// ---------------------------------------------------------------------------
// Kernel 2: per-patch stats. One block = one (batch, patch); 256 threads.
// OOB (f>=513 or t>=1025) contributes 0 (zero-pad happens AFTER the EPS clamp).
// ---------------------------------------------------------------------------
__global__ __launch_bounds__(256) void patch_stats_kernel(
    const float* __restrict__ mag,
    float* __restrict__ kgs,
    float* __restrict__ pl)
{
    const int tid = threadIdx.x;
    const int p   = blockIdx.x;   // 0..2144
    const int b   = blockIdx.y;   // 0..15
    const int fi  = p / NPT;
    const int ti  = p - fi * NPT;
    const int f   = fi * PS + (tid & 15);
    const int t   = ti * PS + (tid >> 4);

    float sv = 0.0f, tv = 0.0f, gv = 0.0f;
    if (f < NFREQ && t < NFRM) {
        const size_t WOFF = (size_t)BATCH * NFRM * NFREQ;
        const size_t base = ((size_t)b * NFRM + t) * NFREQ + f;
        sv = mag[base];
        tv = mag[base + WOFF];
        gv = mag[base + 2 * WOFF];
    }
    float as = fabsf(sv - gv);
    float at = fabsf(tv - gv);
    float sq = (sv - tv) * (sv - tv);

    #pragma unroll
    for (int off = 32; off > 0; off >>= 1) {
        as += __shfl_down(as, off);
        at += __shfl_down(at, off);
        sq += __shfl_down(sq, off);
    }
    __shared__ float red[3][4];
    if ((tid & 63) == 0) {
        const int wv = tid >> 6;
        red[0][wv] = as; red[1][wv] = at; red[2][wv] = sq;
    }
    __syncthreads();
    if (tid == 0) {
        float sas = red[0][0] + red[0][1] + red[0][2] + red[0][3];
        float sat = red[1][0] + red[1][1] + red[1][2] + red[1][3];
        float ssq = red[2][0] + red[2][1] + red[2][2] + red[2][3];
        kgs[b * NPATCH + p] = (sas - sat) * (1.0f / 256.0f);
        pl [b * NPATCH + p] = ssq * (1.0f / 256.0f);
    }
}

// ---------------------------------------------------------------------------
// Kernel 3: per-row top-k via 8-bit MSB radix select (exact, deterministic).
// One block (256 threads) per batch row.
// Selection set = { u > T } ∪ { lowest-index elements with u == T } (jax tie-break).
// ---------------------------------------------------------------------------
__global__ __launch_bounds__(256) void topk_kernel(
    const float* __restrict__ kgs,
    const float* __restrict__ pl,
    float* __restrict__ rowstats)  // [16][3] = {selected_sum, kgs_sum, pos_count}
{
    __shared__ unsigned ukey[NPATCH];
    __shared__ unsigned hist[256];
    __shared__ int      tIdx[NPATCH];
    __shared__ int      tcnt;
    __shared__ unsigned selByte;
    __shared__ float    red[3][4];

    const int tid = threadIdx.x;
    const int b   = blockIdx.x;
    const float* row = kgs + b * NPATCH;
    const float* plrow = pl + b * NPATCH;

    float lsum = 0.0f, lpos = 0.0f;
    for (int i = tid; i < NPATCH; i += 256) {
        float v = row[i];
        lsum += v;
        lpos += (v > 0.0f) ? 1.0f : 0.0f;
        unsigned u = __float_as_uint(v);
        u = (u & 0x80000000u) ? ~u : (u | 0x80000000u);   // order-preserving map
        ukey[i] = u;
    }
    __syncthreads();

    unsigned prefix = 0;
    int rem = TOPK;
    #pragma unroll
    for (int pass = 0; pass < 4; ++pass) {
        const int shift = 24 - 8 * pass;
        const unsigned himask = (pass == 0) ? 0u : (0xFFFFFFFFu << (shift + 8));

        hist[tid] = 0;
        __syncthreads();
        for (int i = tid; i < NPATCH; i += 256) {
            unsigned u = ukey[i];
            if ((u & himask) == (prefix & himask))
                atomicAdd(&hist[(u >> shift) & 255u], 1u);
        }
        __syncthreads();
        // inclusive suffix scan: hist[t] = sum_{j>=t} hist_orig[j]
        for (int off = 1; off < 256; off <<= 1) {
            unsigned v = (tid + off < 256) ? hist[tid + off] : 0u;
            __syncthreads();
            hist[tid] += v;
            __syncthreads();
        }
        unsigned sb  = hist[tid];
        unsigned sb1 = (tid == 255) ? 0u : hist[tid + 1];
        if (sb >= (unsigned)rem && sb1 < (unsigned)rem) selByte = (unsigned)tid;
        __syncthreads();
        const unsigned B = selByte;
        rem -= (int)((B == 255u) ? 0u : hist[B + 1]);
        prefix |= (B << shift);
        __syncthreads();
    }

    const unsigned T = prefix;
    float ssum = 0.0f;
    if (tid == 0) tcnt = 0;
    __syncthreads();
    for (int i = tid; i < NPATCH; i += 256) {
        unsigned u = ukey[i];
        if (u > T) {
            ssum += plrow[i];
        } else if (u == T) {
            int j = atomicAdd(&tcnt, 1);
            tIdx[j] = i;
        }
    }
    __syncthreads();
    const int m = tcnt;
    if (m == rem) {
        for (int j = tid; j < m; j += 256) ssum += plrow[tIdx[j]];
    } else {
        for (int j = tid; j < m; j += 256) {
            const int i = tIdx[j];
            int rank = 0;
            for (int q = 0; q < m; ++q) rank += (tIdx[q] < i) ? 1 : 0;
            if (rank < rem) ssum += plrow[i];
        }
    }

    #pragma unroll
    for (int off = 32; off > 0; off >>= 1) {
        ssum += __shfl_down(ssum, off);
        lsum += __shfl_down(lsum, off);
        lpos += __shfl_down(lpos, off);
    }
    if ((tid & 63) == 0) {
        const int wv = tid >> 6;
        red[0][wv] = ssum; red[1][wv] = lsum; red[2][wv] = lpos;
    }
    __syncthreads();
    if (tid == 0) {
        rowstats[b * 3 + 0] = red[0][0] + red[0][1] + red[0][2] + red[0][3];
        rowstats[b * 3 + 1] = red[1][0] + red[1][1] + red[1][2] + red[1][3];
        rowstats[b * 3 + 2] = red[2][0] + red[2][1] + red[2][2] + red[2][3];
    }
}

// ---------------------------------------------------------------------------
// Kernel 4: final reduction over 16 rows -> 4 scalars.
// ---------------------------------------------------------------------------
__global__ __launch_bounds__(64) void final_kernel(
    const float* __restrict__ rowstats,
    float* __restrict__ out)
{
    const int tid = threadIdx.x;
    float loss = 0.0f, ks = 0.0f, pc = 0.0f;
    if (tid < BATCH) {
        loss = rowstats[tid * 3 + 0] * (1.0f / (float)TOPK);
        ks   = rowstats[tid * 3 + 1];
        pc   = rowstats[tid * 3 + 2];
    }
    #pragma unroll
    for (int off = 32; off > 0; off >>= 1) {
        loss += __shfl_down(loss, off);
        ks   += __shfl_down(ks, off);
        pc   += __shfl_down(pc, off);
    }
    if (tid == 0) {
        out[0] = loss * (1.0f / (float)BATCH);
        out[1] = (float)TOPK / (float)NPATCH;
        out[2] = ks * (1.0f / ((float)BATCH * (float)NPATCH));
        out[3] = pc * (1.0f / ((float)BATCH * (float)NPATCH));
    }
}

// ---------------------------------------------------------------------------
extern "C" void kernel_launch(void* const* d_in, const int* in_sizes, int n_in,
                              void* d_out, int out_size, void* d_ws, size_t ws_size,
                              hipStream_t stream)
{
    const float* s_in = (const float*)d_in[0];
    const float* t_in = (const float*)d_in[1];
    const float* g_in = (const float*)d_in[2];
    float* out = (float*)d_out;

    const size_t magElems = (size_t)3 * BATCH * NFRM * NFREQ;  // 25,239,600
    float* mag = (float*)d_ws;
    float* kgs = mag + magElems;
    float* pl  = kgs + (size_t)BATCH * NPATCH;
    float* rowstats = pl + (size_t)BATCH * NPATCH;

    dim3 g1(513, BATCH, 3);   // frame pairs
    stft_mag_kernel<<<g1, 256, 0, stream>>>(s_in, t_in, g_in, mag);

    dim3 g2(NPATCH, BATCH, 1);
    patch_stats_kernel<<<g2, 256, 0, stream>>>(mag, kgs, pl);

    topk_kernel<<<BATCH, 256, 0, stream>>>(kgs, pl, rowstats);

    final_kernel<<<1, 64, 0, stream>>>(rowstats, out);
}